// Round 1
// baseline (1649.311 us; speedup 1.0000x reference)
//
#include <hip/hip_runtime.h>
#include <hip/hip_bf16.h>
#include <stdint.h>

// ---------------------------------------------------------------------------
// DEER forward, MI355X. Sizes: L=12, B=2, T=512, C=768, F=3072, M=B*T=1024.
// Strategy: bf16 MFMA GEMMs (fp32 accum), analytic JVP instead of FD probe,
// threefry2x32 (partitionable counter mode) to reproduce jax Rademacher v.
// Workspace layout (total ~437.3 MB, 256B-aligned chunks):
//   w1t  bf16 [12][3072][768]   56.6 MB   (W1^T per layer)
//   w2t  bf16 [12][768][3072]   56.6 MB   (W2^T per layer)
//   states f32 [13][1024][768]  40.9 MB
//   a_buf bf16 [12][2048][768]  37.7 MB   (rows 0..1023 = a, 1024.. = du)
//   zh   bf16 [12][2048][3072] 151.0 MB   (z/dz then h/dh in place)
//   resA f32 [12][2048][768]    75.5 MB   (rows 0..1023 = res, 1024.. = A)
//   v    bf16 [12][1024][768]   18.9 MB
// ---------------------------------------------------------------------------

typedef __bf16 bf16;
typedef __bf16 bf16x8 __attribute__((ext_vector_type(8)));
typedef float f32x4 __attribute__((ext_vector_type(4)));

#define LAY_A   1572864   // 2048*768
#define LAY_W   2359296   // 3072*768
#define LAY_Z   6291456   // 2048*3072
#define LAY_S   786432    // 1024*768
#define HALF_Z  3145728   // 1024*3072

#define GLDS16(gp, lp) __builtin_amdgcn_global_load_lds(                      \
    (const __attribute__((address_space(1))) void*)(gp),                      \
    (__attribute__((address_space(3))) void*)(lp), 16, 0, 0)

// ------------------------- threefry2x32 (host+device) ----------------------
#define TF_ROT(x0, x1, n) { x0 += x1; x1 = (x1 << n) | (x1 >> (32 - n)); x1 ^= x0; }
__host__ __device__ __forceinline__ void threefry2x32(
    uint32_t k1, uint32_t k2, uint32_t c0, uint32_t c1, uint32_t& o0, uint32_t& o1)
{
  const uint32_t ks2 = k1 ^ k2 ^ 0x1BD11BDAu;
  uint32_t x0 = c0 + k1, x1 = c1 + k2;
  TF_ROT(x0,x1,13) TF_ROT(x0,x1,15) TF_ROT(x0,x1,26) TF_ROT(x0,x1,6)
  x0 += k2;  x1 += ks2 + 1u;
  TF_ROT(x0,x1,17) TF_ROT(x0,x1,29) TF_ROT(x0,x1,16) TF_ROT(x0,x1,24)
  x0 += ks2; x1 += k1 + 2u;
  TF_ROT(x0,x1,13) TF_ROT(x0,x1,15) TF_ROT(x0,x1,26) TF_ROT(x0,x1,6)
  x0 += k1;  x1 += k2 + 3u;
  TF_ROT(x0,x1,17) TF_ROT(x0,x1,29) TF_ROT(x0,x1,16) TF_ROT(x0,x1,24)
  x0 += k2;  x1 += ks2 + 4u;
  TF_ROT(x0,x1,13) TF_ROT(x0,x1,15) TF_ROT(x0,x1,26) TF_ROT(x0,x1,6)
  x0 += ks2; x1 += k1 + 5u;
  o0 = x0; o1 = x1;
}

// v = sign(normal) == bit31 of random word. Partitionable counter mode:
// bits(i) = o0 ^ o1 of threefry(key, (0, i)).
__global__ __launch_bounds__(256) void genv_kernel(bf16* __restrict__ vbuf,
                                                   uint32_t k1, uint32_t k2)
{
  const uint32_t i = blockIdx.x * 256u + threadIdx.x;
  uint32_t o0, o1;
  threefry2x32(k1, k2, 0u, i, o0, o1);
  const uint32_t bits = o0 ^ o1;
  vbuf[i] = (bits & 0x80000000u) ? (bf16)1.0f : (bf16)(-1.0f);
}

// --------------------- weight transpose fp32 -> bf16^T ---------------------
// w (L, R, Cc) f32 -> wt (L, Cc, R) bf16
__global__ __launch_bounds__(256) void transpose_kernel(
    const float* __restrict__ w, bf16* __restrict__ wt, int R, int Cc)
{
  __shared__ float tile[32][33];
  const int l = blockIdx.z;
  const float* wp = w + (size_t)l * R * Cc;
  bf16* wtp = wt + (size_t)l * R * Cc;
  const int c0 = blockIdx.x * 32;
  const int r0 = blockIdx.y * 32;
  const int tx = threadIdx.x & 31, ty = threadIdx.x >> 5;
  #pragma unroll
  for (int q = 0; q < 4; ++q)
    tile[ty + q * 8][tx] = wp[(size_t)(r0 + ty + q * 8) * Cc + c0 + tx];
  __syncthreads();
  #pragma unroll
  for (int q = 0; q < 4; ++q)
    wtp[(size_t)(c0 + ty + q * 8) * R + r0 + tx] = (bf16)tile[tx][ty + q * 8];
}

// ------------------------------ GEMM core ----------------------------------
// 128x128 tile, BK=64, 256 threads (4 waves in 2x2), 16x16x32 bf16 MFMA.
// A: [M][K] row-major bf16 (pre-offset to tile row m0). B: [N][K] row-major
// bf16 (B^T layout, pre-offset to tile row n0). Linear LDS + global_load_lds.
static __device__ __forceinline__ void gemm_tile_loop(
    const bf16* __restrict__ A, const bf16* __restrict__ B,
    int lda, int ldb, int K, bf16* As, bf16* Bs, f32x4 acc[4][4])
{
  const int tid  = threadIdx.x;
  const int lane = tid & 63;
  const int srow = tid >> 3;      // 0..31
  const int sk8  = tid & 7;       // 8-elem column group
  const int wuni = tid & ~63;     // wave*64 (uniform)
  const int r16  = lane & 15;
  const int hi   = lane >> 4;
  const int wr   = (tid >> 7) & 1;
  const int wc   = (tid >> 6) & 1;
  for (int kt = 0; kt < K; kt += 64) {
    __syncthreads();   // previous tile's reads complete
    #pragma unroll
    for (int j = 0; j < 4; ++j) {
      GLDS16(A + (size_t)(j * 32 + srow) * lda + kt + sk8 * 8,
             (char*)As + j * 4096 + wuni * 16);
      GLDS16(B + (size_t)(j * 32 + srow) * ldb + kt + sk8 * 8,
             (char*)Bs + j * 4096 + wuni * 16);
    }
    __syncthreads();   // compiler drains vmcnt before barrier
    #pragma unroll
    for (int kk = 0; kk < 2; ++kk) {
      bf16x8 af[4], bfr[4];
      #pragma unroll
      for (int mi = 0; mi < 4; ++mi)
        af[mi] = *(const bf16x8*)&As[(wr * 64 + mi * 16 + r16) * 64 + kk * 32 + hi * 8];
      #pragma unroll
      for (int ni = 0; ni < 4; ++ni)
        bfr[ni] = *(const bf16x8*)&Bs[(wc * 64 + ni * 16 + r16) * 64 + kk * 32 + hi * 8];
      #pragma unroll
      for (int mi = 0; mi < 4; ++mi)
        #pragma unroll
        for (int ni = 0; ni < 4; ++ni)
          acc[mi][ni] = __builtin_amdgcn_mfma_f32_16x16x32_bf16(
              af[mi], bfr[ni], acc[mi][ni], 0, 0, 0);
    }
  }
}

// GEMM1: a_buf @ W1^T -> zh (bf16), +b1 on primal rows (<1024)
__global__ __launch_bounds__(256) void gemm1_kernel(
    const bf16* __restrict__ a_buf, const bf16* __restrict__ w1t,
    bf16* __restrict__ zh, const float* __restrict__ b1)
{
  __shared__ bf16 As[128 * 64];
  __shared__ bf16 Bs[128 * 64];
  const int l = blockIdx.z;
  const int m0 = blockIdx.y * 128, n0 = blockIdx.x * 128;
  const bf16* A  = a_buf + (size_t)l * LAY_A + (size_t)m0 * 768;
  const bf16* Bt = w1t   + (size_t)l * LAY_W + (size_t)n0 * 768;
  f32x4 acc[4][4] = {};
  gemm_tile_loop(A, Bt, 768, 768, 768, As, Bs, acc);
  bf16* Cp = zh + (size_t)l * LAY_Z;
  const float* b1p = b1 + l * 3072;
  const int lane = threadIdx.x & 63;
  const int wr = (threadIdx.x >> 7) & 1, wc = (threadIdx.x >> 6) & 1;
  const int hi = lane >> 4, r16 = lane & 15;
  #pragma unroll
  for (int mi = 0; mi < 4; ++mi) {
    const int rowb = m0 + wr * 64 + mi * 16 + hi * 4;
    #pragma unroll
    for (int ni = 0; ni < 4; ++ni) {
      const int col = n0 + wc * 64 + ni * 16 + r16;
      const float bias = (rowb < 1024) ? b1p[col] : 0.f;
      #pragma unroll
      for (int r = 0; r < 4; ++r)
        Cp[(size_t)(rowb + r) * 3072 + col] = (bf16)(acc[mi][ni][r] + bias);
    }
  }
}

// GEMM2: zh(h/dh) @ W2^T. MODE 0 (warm): states[l+1] = acc + b2 + x0.
// MODE 1 (iter): rows<1024 -> res = acc + b2 + s[l] - s[l+1];
//                rows>=1024 -> A = 1 + acc*v.
template <int MODE>
__global__ __launch_bounds__(256) void gemm2_kernel(
    const bf16* __restrict__ zh, const bf16* __restrict__ w2t,
    float* __restrict__ states, float* __restrict__ resA,
    const bf16* __restrict__ vbuf, const float* __restrict__ b2,
    const float* __restrict__ x0)
{
  __shared__ bf16 As[128 * 64];
  __shared__ bf16 Bs[128 * 64];
  const int l = blockIdx.z;
  const int m0 = blockIdx.y * 128, n0 = blockIdx.x * 128;
  const bf16* A  = zh  + (size_t)l * LAY_Z + (size_t)m0 * 3072;
  const bf16* Bt = w2t + (size_t)l * LAY_W + (size_t)n0 * 3072;
  f32x4 acc[4][4] = {};
  gemm_tile_loop(A, Bt, 3072, 3072, 3072, As, Bs, acc);
  const float* b2p = b2 + l * 768;
  const int lane = threadIdx.x & 63;
  const int wr = (threadIdx.x >> 7) & 1, wc = (threadIdx.x >> 6) & 1;
  const int hi = lane >> 4, r16 = lane & 15;
  #pragma unroll
  for (int mi = 0; mi < 4; ++mi) {
    const int rowb = m0 + wr * 64 + mi * 16 + hi * 4;
    #pragma unroll
    for (int ni = 0; ni < 4; ++ni) {
      const int col = n0 + wc * 64 + ni * 16 + r16;
      const float bb = b2p[col];
      #pragma unroll
      for (int r = 0; r < 4; ++r) {
        const int row = rowb + r;
        const float a = acc[mi][ni][r];
        if (MODE == 0) {
          states[(size_t)(l + 1) * LAY_S + (size_t)row * 768 + col] =
              a + bb + x0[(size_t)row * 768 + col];
        } else {
          if (rowb < 1024) {
            resA[(size_t)l * LAY_A + (size_t)row * 768 + col] =
                a + bb + states[(size_t)l * LAY_S + (size_t)row * 768 + col]
                       - states[(size_t)(l + 1) * LAY_S + (size_t)row * 768 + col];
          } else {
            const int rr = row - 1024;
            const float vv = (float)vbuf[(size_t)l * LAY_S + (size_t)rr * 768 + col];
            resA[(size_t)l * LAY_A + (size_t)row * 768 + col] = 1.0f + a * vv;
          }
        }
      }
    }
  }
}

// ------------------------------- LayerNorm ---------------------------------
// warm: xhat(x0) once, write a = xhat*g_l + beta_l for all 12 layers
__global__ __launch_bounds__(256) void ln_warm_kernel(
    const float* __restrict__ x0, const float* __restrict__ g,
    const float* __restrict__ beta, bf16* __restrict__ a_buf)
{
  const int row = blockIdx.x * 4 + (threadIdx.x >> 6);
  const int lane = threadIdx.x & 63;
  const float* x = x0 + (size_t)row * 768;
  float xl[12];
  float s1 = 0.f, s2 = 0.f;
  #pragma unroll
  for (int j = 0; j < 12; ++j) {
    float t = x[lane + 64 * j];
    xl[j] = t; s1 += t; s2 += t * t;
  }
  #pragma unroll
  for (int off = 1; off < 64; off <<= 1) {
    s1 += __shfl_xor(s1, off);
    s2 += __shfl_xor(s2, off);
  }
  const float mu = s1 * (1.f / 768.f);
  const float var = s2 * (1.f / 768.f) - mu * mu;
  const float rstd = rsqrtf(var + 1e-5f);
  float xh[12];
  #pragma unroll
  for (int j = 0; j < 12; ++j) xh[j] = (xl[j] - mu) * rstd;
  for (int l = 0; l < 12; ++l) {
    const float* gp = g + l * 768;
    const float* bp = beta + l * 768;
    bf16* ap = a_buf + (size_t)l * LAY_A + (size_t)row * 768;
    #pragma unroll
    for (int j = 0; j < 12; ++j) {
      const int c = lane + 64 * j;
      ap[c] = (bf16)(xh[j] * gp[c] + bp[c]);
    }
  }
}

// iter: LN + LN-JVP with tangent v.  du = rstd*((v-mv) - xhat*mean(xhat*v))*g
__global__ __launch_bounds__(256) void ln_iter_kernel(
    const float* __restrict__ states, const bf16* __restrict__ vbuf,
    const float* __restrict__ g, const float* __restrict__ beta,
    bf16* __restrict__ a_buf)
{
  const int gr = blockIdx.x * 4 + (threadIdx.x >> 6);
  const int l = gr >> 10;
  const int row = gr & 1023;
  const int lane = threadIdx.x & 63;
  const float* x = states + (size_t)l * LAY_S + (size_t)row * 768;
  const bf16* vp = vbuf + (size_t)l * LAY_S + (size_t)row * 768;
  float xl[12], vl[12];
  float s1 = 0.f, s2 = 0.f, sv = 0.f, sxv = 0.f;
  #pragma unroll
  for (int j = 0; j < 12; ++j) {
    const int c = lane + 64 * j;
    float t = x[c];
    float u = (float)vp[c];
    xl[j] = t; vl[j] = u;
    s1 += t; s2 += t * t; sv += u; sxv += t * u;
  }
  #pragma unroll
  for (int off = 1; off < 64; off <<= 1) {
    s1 += __shfl_xor(s1, off); s2 += __shfl_xor(s2, off);
    sv += __shfl_xor(sv, off); sxv += __shfl_xor(sxv, off);
  }
  const float mu = s1 * (1.f / 768.f);
  const float var = s2 * (1.f / 768.f) - mu * mu;
  const float rstd = rsqrtf(var + 1e-5f);
  const float mv = sv * (1.f / 768.f);
  const float mhv = rstd * (sxv * (1.f / 768.f) - mu * mv);  // mean(xhat*v)
  const float* gp = g + l * 768;
  const float* bp = beta + l * 768;
  bf16* ap = a_buf + (size_t)l * LAY_A + (size_t)row * 768;
  bf16* dp = ap + LAY_S;  // rows 1024..2047
  #pragma unroll
  for (int j = 0; j < 12; ++j) {
    const int c = lane + 64 * j;
    const float xh = (xl[j] - mu) * rstd;
    ap[c] = (bf16)(xh * gp[c] + bp[c]);
    dp[c] = (bf16)(rstd * ((vl[j] - mv) - xh * mhv) * gp[c]);
  }
}

// ------------------------------ gelu / dgelu -------------------------------
template <int WITH_D>
__global__ __launch_bounds__(256) void gelu_kernel(bf16* __restrict__ zh)
{
  const size_t idx = (size_t)blockIdx.x * 256 + threadIdx.x;  // 8-elem chunks
  const size_t layer = idx / 393216;                          // 1024*3072/8
  const size_t o = (idx % 393216) * 8;
  bf16* zp = zh + layer * LAY_Z + o;
  bf16x8 zv = *(bf16x8*)zp;
  bf16x8 dzv;
  if (WITH_D) dzv = *(bf16x8*)(zp + HALF_Z);
  #pragma unroll
  for (int e = 0; e < 8; ++e) {
    const float z = (float)zv[e];
    const float z2 = z * z;
    const float u = 0.7978845608028654f * (z + 0.044715f * z2 * z);
    const float t = tanhf(u);
    zv[e] = (bf16)(0.5f * z * (1.f + t));
    if (WITH_D) {
      const float dg = 0.5f * (1.f + t) +
          0.5f * z * (1.f - t * t) * 0.7978845608028654f * (1.f + 0.134145f * z2);
      dzv[e] = (bf16)(dg * (float)dzv[e]);
    }
  }
  *(bf16x8*)zp = zv;
  if (WITH_D) *(bf16x8*)(zp + HALF_Z) = dzv;
}

// --------------------------- scan + state update ---------------------------
// delta_0 = res_0; delta_l = res_l + A_l*delta_{l-1}; states[l+1] += delta_l
__global__ __launch_bounds__(256) void scan_kernel(
    const float* __restrict__ resA, float* __restrict__ states)
{
  const size_t i = (size_t)blockIdx.x * 256 + threadIdx.x;
  float run = resA[i];
  states[LAY_S + i] += run;
  #pragma unroll
  for (int l = 1; l < 12; ++l) {
    const float b  = resA[(size_t)l * LAY_A + i];
    const float Aa = resA[(size_t)l * LAY_A + LAY_S + i];
    run = b + Aa * run;
    states[(size_t)(l + 1) * LAY_S + i] += run;
  }
}

// ------------------------------- launcher ----------------------------------
extern "C" void kernel_launch(void* const* d_in, const int* in_sizes, int n_in,
                              void* d_out, int out_size, void* d_ws, size_t ws_size,
                              hipStream_t stream)
{
  const float* x0   = (const float*)d_in[0];
  const float* w1   = (const float*)d_in[1];
  const float* b1   = (const float*)d_in[2];
  const float* w2   = (const float*)d_in[3];
  const float* b2   = (const float*)d_in[4];
  const float* g    = (const float*)d_in[5];
  const float* beta = (const float*)d_in[6];

  char* ws = (char*)d_ws;
  size_t off = 0;
  auto alloc = [&](size_t bytes) -> void* {
    void* p = ws + off;
    off += (bytes + 255) & ~(size_t)255;
    return p;
  };
  bf16*  w1t    = (bf16*)alloc(2ULL * 12 * LAY_W);
  bf16*  w2t    = (bf16*)alloc(2ULL * 12 * LAY_W);
  float* states = (float*)alloc(4ULL * 13 * LAY_S);
  bf16*  a_buf  = (bf16*)alloc(2ULL * 12 * LAY_A);
  bf16*  zh     = (bf16*)alloc(2ULL * 12 * LAY_Z);
  float* resA   = (float*)alloc(4ULL * 12 * LAY_A);
  bf16*  vbuf   = (bf16*)alloc(2ULL * 12 * LAY_S);
  // requires ws_size >= ~437.3 MB

  // weights -> bf16 transposed
  transpose_kernel<<<dim3(96, 24, 12), 256, 0, stream>>>(w1, w1t, 768, 3072);
  transpose_kernel<<<dim3(24, 96, 12), 256, 0, stream>>>(w2, w2t, 3072, 768);
  hipMemcpyAsync(states, x0, 4ULL * LAY_S, hipMemcpyDeviceToDevice, stream);

  // warm start: states[l+1] = block_l(x0)
  ln_warm_kernel<<<256, 256, 0, stream>>>(x0, g, beta, a_buf);
  gemm1_kernel<<<dim3(24, 8, 12), 256, 0, stream>>>(a_buf, w1t, zh, b1);
  gelu_kernel<0><<<18432, 256, 0, stream>>>(zh);
  gemm2_kernel<0><<<dim3(6, 8, 12), 256, 0, stream>>>(zh, w2t, states, resA, vbuf, b2, x0);

  for (int it = 0; it < 2; ++it) {
    // folded key: threefry_2x32((0,42), (0,it))
    uint32_t k1, k2;
    threefry2x32(0u, 42u, 0u, (uint32_t)it, k1, k2);
    genv_kernel<<<36864, 256, 0, stream>>>(vbuf, k1, k2);
    ln_iter_kernel<<<3072, 256, 0, stream>>>(states, vbuf, g, beta, a_buf);
    gemm1_kernel<<<dim3(24, 16, 12), 256, 0, stream>>>(a_buf, w1t, zh, b1);
    gelu_kernel<1><<<18432, 256, 0, stream>>>(zh);
    gemm2_kernel<1><<<dim3(6, 16, 12), 256, 0, stream>>>(zh, w2t, states, resA, vbuf, b2, x0);
    scan_kernel<<<3072, 256, 0, stream>>>(resA, states);
  }

  hipMemcpyAsync(d_out, states + 12ULL * LAY_S, 4ULL * LAY_S,
                 hipMemcpyDeviceToDevice, stream);
}

// Round 2
// 1266.532 us; speedup vs baseline: 1.3022x; 1.3022x over previous
//
#include <hip/hip_runtime.h>
#include <hip/hip_bf16.h>
#include <stdint.h>

// ---------------------------------------------------------------------------
// DEER forward, MI355X. L=12, B=2, T=512, C=768, F=3072, M=B*T=1024.
// bf16 MFMA GEMMs (fp32 accum), analytic JVP, threefry2x32 Rademacher v.
// R2: 256x256/BK64/512-thread double-buffered GEMM (depth-1 prefetch,
//     T2 LDS swizzle both-sides, T1 XCD swizzle).
// ---------------------------------------------------------------------------

typedef __bf16 bf16;
typedef __bf16 bf16x8 __attribute__((ext_vector_type(8)));
typedef float f32x4 __attribute__((ext_vector_type(4)));

#define LAY_A   1572864   // 2048*768
#define LAY_W   2359296   // 3072*768
#define LAY_Z   6291456   // 2048*3072
#define LAY_S   786432    // 1024*768
#define HALF_Z  3145728   // 1024*3072

#define GLDS16(gp, lp) __builtin_amdgcn_global_load_lds(                      \
    (const __attribute__((address_space(1))) void*)(gp),                      \
    (__attribute__((address_space(3))) void*)(lp), 16, 0, 0)

// ------------------------- threefry2x32 (host+device) ----------------------
#define TF_ROT(x0, x1, n) { x0 += x1; x1 = (x1 << n) | (x1 >> (32 - n)); x1 ^= x0; }
__host__ __device__ __forceinline__ void threefry2x32(
    uint32_t k1, uint32_t k2, uint32_t c0, uint32_t c1, uint32_t& o0, uint32_t& o1)
{
  const uint32_t ks2 = k1 ^ k2 ^ 0x1BD11BDAu;
  uint32_t x0 = c0 + k1, x1 = c1 + k2;
  TF_ROT(x0,x1,13) TF_ROT(x0,x1,15) TF_ROT(x0,x1,26) TF_ROT(x0,x1,6)
  x0 += k2;  x1 += ks2 + 1u;
  TF_ROT(x0,x1,17) TF_ROT(x0,x1,29) TF_ROT(x0,x1,16) TF_ROT(x0,x1,24)
  x0 += ks2; x1 += k1 + 2u;
  TF_ROT(x0,x1,13) TF_ROT(x0,x1,15) TF_ROT(x0,x1,26) TF_ROT(x0,x1,6)
  x0 += k1;  x1 += k2 + 3u;
  TF_ROT(x0,x1,17) TF_ROT(x0,x1,29) TF_ROT(x0,x1,16) TF_ROT(x0,x1,24)
  x0 += k2;  x1 += ks2 + 4u;
  TF_ROT(x0,x1,13) TF_ROT(x0,x1,15) TF_ROT(x0,x1,26) TF_ROT(x0,x1,6)
  x0 += ks2; x1 += k1 + 5u;
  o0 = x0; o1 = x1;
}

__global__ __launch_bounds__(256) void genv_kernel(bf16* __restrict__ vbuf,
                                                   uint32_t k1, uint32_t k2)
{
  const uint32_t i = blockIdx.x * 256u + threadIdx.x;
  uint32_t o0, o1;
  threefry2x32(k1, k2, 0u, i, o0, o1);
  const uint32_t bits = o0 ^ o1;
  vbuf[i] = (bits & 0x80000000u) ? (bf16)1.0f : (bf16)(-1.0f);
}

// --------------------- weight transpose fp32 -> bf16^T ---------------------
__global__ __launch_bounds__(256) void transpose_kernel(
    const float* __restrict__ w, bf16* __restrict__ wt, int R, int Cc)
{
  __shared__ float tile[32][33];
  const int l = blockIdx.z;
  const float* wp = w + (size_t)l * R * Cc;
  bf16* wtp = wt + (size_t)l * R * Cc;
  const int c0 = blockIdx.x * 32;
  const int r0 = blockIdx.y * 32;
  const int tx = threadIdx.x & 31, ty = threadIdx.x >> 5;
  #pragma unroll
  for (int q = 0; q < 4; ++q)
    tile[ty + q * 8][tx] = wp[(size_t)(r0 + ty + q * 8) * Cc + c0 + tx];
  __syncthreads();
  #pragma unroll
  for (int q = 0; q < 4; ++q)
    wtp[(size_t)(c0 + ty + q * 8) * R + r0 + tx] = (bf16)tile[tx][ty + q * 8];
}

// ------------------------------ GEMM core ----------------------------------
// 256x256 tile, BK=64, 512 threads = 8 waves (2M x 4N), per-wave 128x64 out.
// A: [M][K] bf16 row-major, B: [N][K] bf16 (B^T layout). LDS double-buffered,
// T2 swizzle: global chunk (lane&7)^(lane>>3) -> linear GLDS dest; ds_read
// applies the same XOR. One __syncthreads per K-tile; next tile's loads fly
// under the current tile's MFMA phase (depth-1 prefetch).
// MODE 0: gemm1 (out zh bf16 + b1 on rows<1024). K=768, N=3072.
// MODE 1: gemm2 warm (states[l+1] = acc + b2 + x0). K=3072, N=768.
// MODE 2: gemm2 iter (res / A epilogue).        K=3072, N=768.
template <int MODE>
__global__ __launch_bounds__(512, 2) void gemm_dbuf(
    const bf16* __restrict__ Abase, const bf16* __restrict__ Bbase,
    bf16* __restrict__ zh_out, float* __restrict__ states,
    float* __restrict__ resA, const bf16* __restrict__ vbuf,
    const float* __restrict__ bias1, const float* __restrict__ b2,
    const float* __restrict__ x0, int Mt)
{
  constexpr int LDA = (MODE == 0) ? 768 : 3072;   // == LDB for both gemms
  constexpr int NKT = (MODE == 0) ? 12 : 48;      // K/64
  constexpr int NTN = (MODE == 0) ? 12 : 3;       // N/256
  constexpr size_t LSA = (MODE == 0) ? LAY_A : LAY_Z;

  __shared__ bf16 lds[2][2 * 16384];   // [dbuf][A(16384) | B(16384)] = 128 KiB

  const int tid  = threadIdx.x;
  const int lane = tid & 63;
  const int wid  = tid >> 6;           // 0..7
  const int wr   = wid >> 2;           // 0..1  (M half)
  const int wc   = wid & 3;            // 0..3  (N quarter)
  const int r16  = lane & 15;
  const int hi   = lane >> 4;          // 0..3

  // T1: XCD-aware bijective swizzle (grid always a multiple of 8)
  const int nwg = gridDim.x;
  const int bid = blockIdx.x;
  const int swz = (bid & 7) * (nwg >> 3) + (bid >> 3);
  const int per_l = Mt * NTN;
  const int l  = swz / per_l;
  const int rr_ = swz - l * per_l;
  const int mt = rr_ / NTN;
  const int nt = rr_ - mt * NTN;
  const int m0 = mt * 256, n0 = nt * 256;

  const bf16* A = Abase + (size_t)l * LSA   + (size_t)m0 * LDA;
  const bf16* B = Bbase + (size_t)l * LAY_W + (size_t)n0 * LDA;

  // staging: chunk = j*8+wid covers rows 8c..8c+7; lane reads swizzled slot
  const int rsub = lane >> 3;               // 0..7 row within chunk
  const int c8   = (lane & 7) ^ rsub;       // swizzled 16B slot (involution)
  auto STAGE = [&](bf16* dst, int kt) {
    #pragma unroll
    for (int j = 0; j < 4; ++j) {
      const int chunk = j * 8 + wid;
      const int row = chunk * 8 + rsub;
      GLDS16(A + (size_t)row * LDA + kt + c8 * 8, (char*)dst + chunk * 1024);
      GLDS16(B + (size_t)row * LDA + kt + c8 * 8,
             (char*)(dst + 16384) + chunk * 1024);
    }
  };

  f32x4 acc[8][4] = {};

  auto COMPUTE = [&](const bf16* buf) {
    const bf16* As = buf;
    const bf16* Bs = buf + 16384;
    const int xw = (r16 & 7) << 4;        // read-side XOR (matches staging)
    #pragma unroll
    for (int kk = 0; kk < 2; ++kk) {
      const int cb = kk * 64;             // byte col base within 128B row
      bf16x8 bfrag[4];
      #pragma unroll
      for (int ni = 0; ni < 4; ++ni) {
        const int rn = wc * 64 + ni * 16 + r16;
        bfrag[ni] = *(const bf16x8*)((const char*)Bs + rn * 128 +
                                     ((cb + hi * 16) ^ xw));
      }
      #pragma unroll
      for (int mh = 0; mh < 2; ++mh) {
        bf16x8 afrag[4];
        #pragma unroll
        for (int q = 0; q < 4; ++q) {
          const int rm = wr * 128 + (mh * 4 + q) * 16 + r16;
          afrag[q] = *(const bf16x8*)((const char*)As + rm * 128 +
                                      ((cb + hi * 16) ^ xw));
        }
        #pragma unroll
        for (int q = 0; q < 4; ++q)
          #pragma unroll
          for (int ni = 0; ni < 4; ++ni)
            acc[mh * 4 + q][ni] = __builtin_amdgcn_mfma_f32_16x16x32_bf16(
                afrag[q], bfrag[ni], acc[mh * 4 + q][ni], 0, 0, 0);
      }
    }
  };

  STAGE(lds[0], 0);
  __syncthreads();                       // tile 0 resident
  #pragma unroll 1
  for (int t = 0; t < NKT; t += 2) {
    STAGE(lds[1], (t + 1) * 64);         // prefetch t+1 under compute(t)
    COMPUTE(lds[0]);
    __syncthreads();                     // drain t+1 loads; t reads done
    if (t + 2 < NKT) STAGE(lds[0], (t + 2) * 64);
    COMPUTE(lds[1]);
    __syncthreads();
  }

  // ------------------------------ epilogue ---------------------------------
  #pragma unroll
  for (int mi = 0; mi < 8; ++mi) {
    const int row0 = m0 + wr * 128 + mi * 16 + hi * 4;
    #pragma unroll
    for (int ni = 0; ni < 4; ++ni) {
      const int col = n0 + wc * 64 + ni * 16 + r16;
      if (MODE == 0) {
        bf16* Cp = zh_out + (size_t)l * LAY_Z;
        const float bias = (row0 < 1024) ? bias1[l * 3072 + col] : 0.f;
        #pragma unroll
        for (int r = 0; r < 4; ++r)
          Cp[(size_t)(row0 + r) * 3072 + col] = (bf16)(acc[mi][ni][r] + bias);
      } else if (MODE == 1) {
        float* Sp = states + (size_t)(l + 1) * LAY_S;
        const float bb = b2[l * 768 + col];
        #pragma unroll
        for (int r = 0; r < 4; ++r)
          Sp[(size_t)(row0 + r) * 768 + col] =
              acc[mi][ni][r] + bb + x0[(size_t)(row0 + r) * 768 + col];
      } else {
        float* Rp = resA + (size_t)l * LAY_A;
        const float bb = b2[l * 768 + col];
        if (row0 < 1024) {
          #pragma unroll
          for (int r = 0; r < 4; ++r) {
            const int row = row0 + r;
            Rp[(size_t)row * 768 + col] = acc[mi][ni][r] + bb
                + states[(size_t)l * LAY_S + (size_t)row * 768 + col]
                - states[(size_t)(l + 1) * LAY_S + (size_t)row * 768 + col];
          }
        } else {
          #pragma unroll
          for (int r = 0; r < 4; ++r) {
            const int row = row0 + r;
            const float vv = (float)vbuf[(size_t)l * LAY_S +
                                         (size_t)(row - 1024) * 768 + col];
            Rp[(size_t)row * 768 + col] = 1.0f + acc[mi][ni][r] * vv;
          }
        }
      }
    }
  }
}

// ------------------------------- LayerNorm ---------------------------------
__global__ __launch_bounds__(256) void ln_warm_kernel(
    const float* __restrict__ x0, const float* __restrict__ g,
    const float* __restrict__ beta, bf16* __restrict__ a_buf)
{
  const int row = blockIdx.x * 4 + (threadIdx.x >> 6);
  const int lane = threadIdx.x & 63;
  const float* x = x0 + (size_t)row * 768;
  float xl[12];
  float s1 = 0.f, s2 = 0.f;
  #pragma unroll
  for (int j = 0; j < 12; ++j) {
    float t = x[lane + 64 * j];
    xl[j] = t; s1 += t; s2 += t * t;
  }
  #pragma unroll
  for (int off = 1; off < 64; off <<= 1) {
    s1 += __shfl_xor(s1, off);
    s2 += __shfl_xor(s2, off);
  }
  const float mu = s1 * (1.f / 768.f);
  const float var = s2 * (1.f / 768.f) - mu * mu;
  const float rstd = rsqrtf(var + 1e-5f);
  float xh[12];
  #pragma unroll
  for (int j = 0; j < 12; ++j) xh[j] = (xl[j] - mu) * rstd;
  for (int l = 0; l < 12; ++l) {
    const float* gp = g + l * 768;
    const float* bp = beta + l * 768;
    bf16* ap = a_buf + (size_t)l * LAY_A + (size_t)row * 768;
    #pragma unroll
    for (int j = 0; j < 12; ++j) {
      const int c = lane + 64 * j;
      ap[c] = (bf16)(xh[j] * gp[c] + bp[c]);
    }
  }
}

__global__ __launch_bounds__(256) void ln_iter_kernel(
    const float* __restrict__ states, const bf16* __restrict__ vbuf,
    const float* __restrict__ g, const float* __restrict__ beta,
    bf16* __restrict__ a_buf)
{
  const int gr = blockIdx.x * 4 + (threadIdx.x >> 6);
  const int l = gr >> 10;
  const int row = gr & 1023;
  const int lane = threadIdx.x & 63;
  const float* x = states + (size_t)l * LAY_S + (size_t)row * 768;
  const bf16* vp = vbuf + (size_t)l * LAY_S + (size_t)row * 768;
  float xl[12], vl[12];
  float s1 = 0.f, s2 = 0.f, sv = 0.f, sxv = 0.f;
  #pragma unroll
  for (int j = 0; j < 12; ++j) {
    const int c = lane + 64 * j;
    float t = x[c];
    float u = (float)vp[c];
    xl[j] = t; vl[j] = u;
    s1 += t; s2 += t * t; sv += u; sxv += t * u;
  }
  #pragma unroll
  for (int off = 1; off < 64; off <<= 1) {
    s1 += __shfl_xor(s1, off); s2 += __shfl_xor(s2, off);
    sv += __shfl_xor(sv, off); sxv += __shfl_xor(sxv, off);
  }
  const float mu = s1 * (1.f / 768.f);
  const float var = s2 * (1.f / 768.f) - mu * mu;
  const float rstd = rsqrtf(var + 1e-5f);
  const float mv = sv * (1.f / 768.f);
  const float mhv = rstd * (sxv * (1.f / 768.f) - mu * mv);
  const float* gp = g + l * 768;
  const float* bp = beta + l * 768;
  bf16* ap = a_buf + (size_t)l * LAY_A + (size_t)row * 768;
  bf16* dp = ap + LAY_S;
  #pragma unroll
  for (int j = 0; j < 12; ++j) {
    const int c = lane + 64 * j;
    const float xh = (xl[j] - mu) * rstd;
    ap[c] = (bf16)(xh * gp[c] + bp[c]);
    dp[c] = (bf16)(rstd * ((vl[j] - mv) - xh * mhv) * gp[c]);
  }
}

// ------------------------------ gelu / dgelu -------------------------------
template <int WITH_D>
__global__ __launch_bounds__(256) void gelu_kernel(bf16* __restrict__ zh)
{
  const size_t idx = (size_t)blockIdx.x * 256 + threadIdx.x;
  const size_t layer = idx / 393216;
  const size_t o = (idx % 393216) * 8;
  bf16* zp = zh + layer * LAY_Z + o;
  bf16x8 zv = *(bf16x8*)zp;
  bf16x8 dzv;
  if (WITH_D) dzv = *(bf16x8*)(zp + HALF_Z);
  #pragma unroll
  for (int e = 0; e < 8; ++e) {
    const float z = (float)zv[e];
    const float z2 = z * z;
    const float u = 0.7978845608028654f * (z + 0.044715f * z2 * z);
    const float t = tanhf(u);
    zv[e] = (bf16)(0.5f * z * (1.f + t));
    if (WITH_D) {
      const float dg = 0.5f * (1.f + t) +
          0.5f * z * (1.f - t * t) * 0.7978845608028654f * (1.f + 0.134145f * z2);
      dzv[e] = (bf16)(dg * (float)dzv[e]);
    }
  }
  *(bf16x8*)zp = zv;
  if (WITH_D) *(bf16x8*)(zp + HALF_Z) = dzv;
}

// --------------------------- scan + state update ---------------------------
__global__ __launch_bounds__(256) void scan_kernel(
    const float* __restrict__ resA, float* __restrict__ states)
{
  const size_t i = (size_t)blockIdx.x * 256 + threadIdx.x;
  float run = resA[i];
  states[LAY_S + i] += run;
  #pragma unroll
  for (int l = 1; l < 12; ++l) {
    const float b  = resA[(size_t)l * LAY_A + i];
    const float Aa = resA[(size_t)l * LAY_A + LAY_S + i];
    run = b + Aa * run;
    states[(size_t)(l + 1) * LAY_S + i] += run;
  }
}

// ------------------------------- launcher ----------------------------------
extern "C" void kernel_launch(void* const* d_in, const int* in_sizes, int n_in,
                              void* d_out, int out_size, void* d_ws, size_t ws_size,
                              hipStream_t stream)
{
  const float* x0   = (const float*)d_in[0];
  const float* w1   = (const float*)d_in[1];
  const float* b1   = (const float*)d_in[2];
  const float* w2   = (const float*)d_in[3];
  const float* b2   = (const float*)d_in[4];
  const float* g    = (const float*)d_in[5];
  const float* beta = (const float*)d_in[6];

  char* ws = (char*)d_ws;
  size_t off = 0;
  auto alloc = [&](size_t bytes) -> void* {
    void* p = ws + off;
    off += (bytes + 255) & ~(size_t)255;
    return p;
  };
  bf16*  w1t    = (bf16*)alloc(2ULL * 12 * LAY_W);
  bf16*  w2t    = (bf16*)alloc(2ULL * 12 * LAY_W);
  float* states = (float*)alloc(4ULL * 13 * LAY_S);
  bf16*  a_buf  = (bf16*)alloc(2ULL * 12 * LAY_A);
  bf16*  zh     = (bf16*)alloc(2ULL * 12 * LAY_Z);
  float* resA   = (float*)alloc(4ULL * 12 * LAY_A);
  bf16*  vbuf   = (bf16*)alloc(2ULL * 12 * LAY_S);

  transpose_kernel<<<dim3(96, 24, 12), 256, 0, stream>>>(w1, w1t, 768, 3072);
  transpose_kernel<<<dim3(24, 96, 12), 256, 0, stream>>>(w2, w2t, 3072, 768);
  hipMemcpyAsync(states, x0, 4ULL * LAY_S, hipMemcpyDeviceToDevice, stream);

  // warm start: states[l+1] = block_l(x0)
  ln_warm_kernel<<<256, 256, 0, stream>>>(x0, g, beta, a_buf);
  gemm_dbuf<0><<<576, 512, 0, stream>>>(a_buf, w1t, zh, states, resA, vbuf,
                                        b1, b2, x0, 4);
  gelu_kernel<0><<<18432, 256, 0, stream>>>(zh);
  gemm_dbuf<1><<<144, 512, 0, stream>>>(zh, w2t, nullptr, states, resA, vbuf,
                                        b1, b2, x0, 4);

  for (int it = 0; it < 2; ++it) {
    uint32_t k1, k2;
    threefry2x32(0u, 42u, 0u, (uint32_t)it, k1, k2);
    genv_kernel<<<36864, 256, 0, stream>>>(vbuf, k1, k2);
    ln_iter_kernel<<<3072, 256, 0, stream>>>(states, vbuf, g, beta, a_buf);
    gemm_dbuf<0><<<1152, 512, 0, stream>>>(a_buf, w1t, zh, states, resA, vbuf,
                                           b1, b2, x0, 8);
    gelu_kernel<1><<<18432, 256, 0, stream>>>(zh);
    gemm_dbuf<2><<<288, 512, 0, stream>>>(zh, w2t, nullptr, states, resA, vbuf,
                                          b1, b2, x0, 8);
    scan_kernel<<<3072, 256, 0, stream>>>(resA, states);
  }

  hipMemcpyAsync(d_out, states + 12ULL * LAY_S, 4ULL * LAY_S,
                 hipMemcpyDeviceToDevice, stream);
}

// Round 4
// 1156.107 us; speedup vs baseline: 1.4266x; 1.0955x over previous
//
#include <hip/hip_runtime.h>
#include <hip/hip_bf16.h>
#include <stdint.h>

// ---------------------------------------------------------------------------
// DEER forward, MI355X. L=12, B=2, T=512, C=768, F=3072, M=B*T=1024.
// bf16 MFMA GEMMs (fp32 accum), analytic JVP, threefry2x32 Rademacher v.
// R4: R2's proven syncthreads double-buffer GEMM core (absmax 0.25) +
//     fused epilogues only: gelu/dgelu in gemm1 (interleaved rows, token
//     bug FIXED: tok = row0/2 + p), genv inside ln_iter, gemm2-iter 256x128.
// ---------------------------------------------------------------------------

typedef __bf16 bf16;
typedef __bf16 bf16x8 __attribute__((ext_vector_type(8)));
typedef float f32x4 __attribute__((ext_vector_type(4)));

#define LAY_A   1572864   // 2048*768
#define LAY_W   2359296   // 3072*768
#define LAY_Z   6291456   // 2048*3072
#define LAY_S   786432    // 1024*768

#define GLDS16(gp, lp) __builtin_amdgcn_global_load_lds(                      \
    (const __attribute__((address_space(1))) void*)(gp),                      \
    (__attribute__((address_space(3))) void*)(lp), 16, 0, 0)

// ------------------------- threefry2x32 (host+device) ----------------------
#define TF_ROT(x0, x1, n) { x0 += x1; x1 = (x1 << n) | (x1 >> (32 - n)); x1 ^= x0; }
__host__ __device__ __forceinline__ void threefry2x32(
    uint32_t k1, uint32_t k2, uint32_t c0, uint32_t c1, uint32_t& o0, uint32_t& o1)
{
  const uint32_t ks2 = k1 ^ k2 ^ 0x1BD11BDAu;
  uint32_t x0 = c0 + k1, x1 = c1 + k2;
  TF_ROT(x0,x1,13) TF_ROT(x0,x1,15) TF_ROT(x0,x1,26) TF_ROT(x0,x1,6)
  x0 += k2;  x1 += ks2 + 1u;
  TF_ROT(x0,x1,17) TF_ROT(x0,x1,29) TF_ROT(x0,x1,16) TF_ROT(x0,x1,24)
  x0 += ks2; x1 += k1 + 2u;
  TF_ROT(x0,x1,13) TF_ROT(x0,x1,15) TF_ROT(x0,x1,26) TF_ROT(x0,x1,6)
  x0 += k1;  x1 += k2 + 3u;
  TF_ROT(x0,x1,17) TF_ROT(x0,x1,29) TF_ROT(x0,x1,16) TF_ROT(x0,x1,24)
  x0 += k2;  x1 += ks2 + 4u;
  TF_ROT(x0,x1,13) TF_ROT(x0,x1,15) TF_ROT(x0,x1,26) TF_ROT(x0,x1,6)
  x0 += ks2; x1 += k1 + 5u;
  o0 = x0; o1 = x1;
}

// --------------------- weight transpose fp32 -> bf16^T ---------------------
__global__ __launch_bounds__(256) void transpose_kernel(
    const float* __restrict__ w, bf16* __restrict__ wt, int R, int Cc)
{
  __shared__ float tile[32][33];
  const int l = blockIdx.z;
  const float* wp = w + (size_t)l * R * Cc;
  bf16* wtp = wt + (size_t)l * R * Cc;
  const int c0 = blockIdx.x * 32;
  const int r0 = blockIdx.y * 32;
  const int tx = threadIdx.x & 31, ty = threadIdx.x >> 5;
  #pragma unroll
  for (int q = 0; q < 4; ++q)
    tile[ty + q * 8][tx] = wp[(size_t)(r0 + ty + q * 8) * Cc + c0 + tx];
  __syncthreads();
  #pragma unroll
  for (int q = 0; q < 4; ++q)
    wtp[(size_t)(c0 + ty + q * 8) * R + r0 + tx] = (bf16)tile[tx][ty + q * 8];
}

// ------------------------------ gelu helper --------------------------------
__device__ __forceinline__ void gelu2(float z, float& h, float& dg)
{
  const float z2 = z * z;
  const float u = 0.7978845608028654f * (z + 0.044715f * z2 * z);
  const float t = tanhf(u);
  h = 0.5f * z * (1.f + t);
  dg = 0.5f * (1.f + t) +
       0.5f * z * (1.f - t * t) * 0.7978845608028654f * (1.f + 0.134145f * z2);
}

// ------------------------------ GEMM core ----------------------------------
// 256xTN tile, BK=64, 512 threads = 8 waves (2M x 4N). R2-proven structure:
// depth-1 prefetch via STAGE(buf^1) -> COMPUTE(buf) -> __syncthreads().
// T2 swizzle: global 16B slot (lane&7)^(row&7) -> linear GLDS dest; ds_read
// applies the same XOR.  T1 XCD swizzle on blockIdx.
// MODE 0: gemm1 warm  (M=1024): zh = gelu(acc + b1), all rows.
// MODE 1: gemm1 iter  (M=2048 interleaved): even h=gelu(z), odd dh=dg*dz.
// MODE 2: gemm2 warm : states[l+1] = acc + b2 + x0.
// MODE 3: gemm2 iter  (TN=128, interleaved): even res, odd A = 1 + acc*v.
template <int MODE>
__global__ __launch_bounds__(512, 2) void gemm_dbuf(
    const bf16* __restrict__ Abase, const bf16* __restrict__ Bbase,
    bf16* __restrict__ zh_out, float* __restrict__ states,
    float* __restrict__ resA, const bf16* __restrict__ vbuf,
    const float* __restrict__ bias1, const float* __restrict__ b2,
    const float* __restrict__ x0, int Mt)
{
  constexpr int LDAB  = (MODE <= 1) ? 768 : 3072;
  constexpr int NKT   = (MODE <= 1) ? 12 : 48;      // K/64
  constexpr int NTN   = (MODE <= 1) ? 12 : ((MODE == 2) ? 3 : 6);
  constexpr int TN    = (MODE == 3) ? 128 : 256;
  constexpr int NFRAG = TN / 64;
  constexpr int ACH   = 32;                 // A chunks (256 rows / 8)
  constexpr int BCH   = TN / 8;             // B chunks
  constexpr int NCH   = (ACH + BCH) / 8;    // loads per thread per tile
  constexpr int ABYTES = 32768;
  constexpr int TILE  = ABYTES + BCH * 1024;
  constexpr size_t LSA = (MODE <= 1) ? LAY_A : LAY_Z;

  __shared__ __align__(16) char lds[2][TILE];

  const int tid  = threadIdx.x;
  const int lane = tid & 63;
  const int wid  = tid >> 6;           // 0..7
  const int wr   = wid >> 2;           // 0..1  (M half)
  const int wc   = wid & 3;            // 0..3  (N quarter)
  const int r16  = lane & 15;
  const int hi   = lane >> 4;          // 0..3

  // T1: XCD-aware bijective swizzle (grids are multiples of 8)
  const int nwg = gridDim.x;
  const int bid = blockIdx.x;
  const int swz = (bid & 7) * (nwg >> 3) + (bid >> 3);
  const int per_l = Mt * NTN;
  const int l   = swz / per_l;
  const int rr_ = swz - l * per_l;
  const int mt  = rr_ / NTN;
  const int nt  = rr_ - mt * NTN;
  const int m0  = mt * 256, n0 = nt * TN;

  const bf16* A = Abase + (size_t)l * LSA   + (size_t)m0 * LDAB;
  const bf16* B = Bbase + (size_t)l * LAY_W + (size_t)n0 * LDAB;

  const int rsub = lane >> 3;               // 0..7 row within chunk
  const int c8   = (lane & 7) ^ rsub;       // swizzled 16B slot (involution)
  auto STAGE = [&](char* dst, int kt) {
    #pragma unroll
    for (int j = 0; j < NCH; ++j) {
      const int chunk = j * 8 + wid;
      if (chunk < ACH) {
        const int row = chunk * 8 + rsub;
        GLDS16(A + (size_t)row * LDAB + kt + c8 * 8, dst + chunk * 1024);
      } else {
        const int row = (chunk - ACH) * 8 + rsub;
        GLDS16(B + (size_t)row * LDAB + kt + c8 * 8,
               dst + ABYTES + (chunk - ACH) * 1024);
      }
    }
  };

  f32x4 acc[8][NFRAG] = {};

  auto COMPUTE = [&](const char* buf) {
    const char* As = buf;
    const char* Bs = buf + ABYTES;
    const int xw = (r16 & 7) << 4;        // read-side XOR (matches staging)
    #pragma unroll
    for (int kk = 0; kk < 2; ++kk) {
      const int cb = kk * 64;
      bf16x8 bfrag[NFRAG];
      #pragma unroll
      for (int ni = 0; ni < NFRAG; ++ni) {
        const int rn = wc * (TN / 4) + ni * 16 + r16;
        bfrag[ni] = *(const bf16x8*)(Bs + rn * 128 + ((cb + hi * 16) ^ xw));
      }
      #pragma unroll
      for (int mh = 0; mh < 2; ++mh) {
        bf16x8 afrag[4];
        #pragma unroll
        for (int q = 0; q < 4; ++q) {
          const int rm = wr * 128 + (mh * 4 + q) * 16 + r16;
          afrag[q] = *(const bf16x8*)(As + rm * 128 + ((cb + hi * 16) ^ xw));
        }
        #pragma unroll
        for (int q = 0; q < 4; ++q)
          #pragma unroll
          for (int ni = 0; ni < NFRAG; ++ni)
            acc[mh * 4 + q][ni] = __builtin_amdgcn_mfma_f32_16x16x32_bf16(
                afrag[q], bfrag[ni], acc[mh * 4 + q][ni], 0, 0, 0);
      }
    }
  };

  STAGE(lds[0], 0);
  __syncthreads();                       // tile 0 resident
  #pragma unroll 1
  for (int t = 0; t < NKT; t += 2) {
    STAGE(lds[1], (t + 1) * 64);         // prefetch t+1 under compute(t)
    COMPUTE(lds[0]);
    __syncthreads();
    if (t + 2 < NKT) STAGE(lds[0], (t + 2) * 64);
    COMPUTE(lds[1]);
    __syncthreads();
  }

  // ------------------------------ epilogue ---------------------------------
  #pragma unroll
  for (int mi = 0; mi < 8; ++mi) {
    const int row0 = m0 + wr * 128 + mi * 16 + hi * 4;
    #pragma unroll
    for (int ni = 0; ni < NFRAG; ++ni) {
      const int col = n0 + wc * (TN / 4) + ni * 16 + r16;
      if (MODE == 0) {                  // warm gemm1: h = gelu(z), all rows
        bf16* Cp = zh_out + (size_t)l * LAY_Z;
        const float bias = bias1[l * 3072 + col];
        #pragma unroll
        for (int r = 0; r < 4; ++r) {
          float h, dg;
          gelu2(acc[mi][ni][r] + bias, h, dg);
          Cp[(size_t)(row0 + r) * 3072 + col] = (bf16)h;
        }
      } else if (MODE == 1) {           // iter gemm1: row pairs (z, dz)
        bf16* Cp = zh_out + (size_t)l * LAY_Z;
        const float bias = bias1[l * 3072 + col];
        #pragma unroll
        for (int p = 0; p < 2; ++p) {
          float h, dg;
          gelu2(acc[mi][ni][2 * p] + bias, h, dg);
          Cp[(size_t)(row0 + 2 * p) * 3072 + col] = (bf16)h;
          Cp[(size_t)(row0 + 2 * p + 1) * 3072 + col] =
              (bf16)(dg * acc[mi][ni][2 * p + 1]);
        }
      } else if (MODE == 2) {           // warm gemm2
        float* Sp = states + (size_t)(l + 1) * LAY_S;
        const float bb = b2[l * 768 + col];
        #pragma unroll
        for (int r = 0; r < 4; ++r)
          Sp[(size_t)(row0 + r) * 768 + col] =
              acc[mi][ni][r] + bb + x0[(size_t)(row0 + r) * 768 + col];
      } else {                          // iter gemm2: row pairs (res, Adiag)
        float* Rp = resA + (size_t)l * LAY_A;
        const float bb = b2[l * 768 + col];
        #pragma unroll
        for (int p = 0; p < 2; ++p) {
          const int tok = (row0 >> 1) + p;          // rows row0+2p, +2p+1
          Rp[(size_t)tok * 768 + col] = acc[mi][ni][2 * p] + bb
              + states[(size_t)l * LAY_S + (size_t)tok * 768 + col]
              - states[(size_t)(l + 1) * LAY_S + (size_t)tok * 768 + col];
          const float vv = (float)vbuf[(size_t)l * LAY_S +
                                       (size_t)tok * 768 + col];
          Rp[LAY_S + (size_t)tok * 768 + col] =
              1.0f + acc[mi][ni][2 * p + 1] * vv;
        }
      }
    }
  }
}

// ------------------------------- LayerNorm ---------------------------------
__global__ __launch_bounds__(256) void ln_warm_kernel(
    const float* __restrict__ x0, const float* __restrict__ g,
    const float* __restrict__ beta, bf16* __restrict__ a_buf)
{
  const int row = blockIdx.x * 4 + (threadIdx.x >> 6);
  const int lane = threadIdx.x & 63;
  const float* x = x0 + (size_t)row * 768;
  float xl[12];
  float s1 = 0.f, s2 = 0.f;
  #pragma unroll
  for (int j = 0; j < 12; ++j) {
    float t = x[lane + 64 * j];
    xl[j] = t; s1 += t; s2 += t * t;
  }
  #pragma unroll
  for (int off = 1; off < 64; off <<= 1) {
    s1 += __shfl_xor(s1, off);
    s2 += __shfl_xor(s2, off);
  }
  const float mu = s1 * (1.f / 768.f);
  const float var = s2 * (1.f / 768.f) - mu * mu;
  const float rstd = rsqrtf(var + 1e-5f);
  float xh[12];
  #pragma unroll
  for (int j = 0; j < 12; ++j) xh[j] = (xl[j] - mu) * rstd;
  for (int l = 0; l < 12; ++l) {
    const float* gp = g + l * 768;
    const float* bp = beta + l * 768;
    bf16* ap = a_buf + (size_t)l * LAY_A + (size_t)row * 768;
    #pragma unroll
    for (int j = 0; j < 12; ++j) {
      const int c = lane + 64 * j;
      ap[c] = (bf16)(xh[j] * gp[c] + bp[c]);
    }
  }
}

// iter: LN + LN-JVP with tangent v (v generated inline via threefry).
// Writes interleaved rows: token row -> a at 2*row, du at 2*row+1.
__global__ __launch_bounds__(256) void ln_iter_kernel(
    const float* __restrict__ states, bf16* __restrict__ vbuf,
    const float* __restrict__ g, const float* __restrict__ beta,
    bf16* __restrict__ a_buf, uint32_t k1, uint32_t k2)
{
  const int gr = blockIdx.x * 4 + (threadIdx.x >> 6);
  const int l = gr >> 10;
  const int row = gr & 1023;
  const int lane = threadIdx.x & 63;
  const float* x = states + (size_t)l * LAY_S + (size_t)row * 768;
  bf16* vp = vbuf + (size_t)gr * 768;
  float xl[12], vl[12];
  float s1 = 0.f, s2 = 0.f, sv = 0.f, sxv = 0.f;
  #pragma unroll
  for (int j = 0; j < 12; ++j) {
    const int c = lane + 64 * j;
    const float t = x[c];
    uint32_t o0, o1;
    threefry2x32(k1, k2, 0u, (uint32_t)gr * 768u + (uint32_t)c, o0, o1);
    const float u = ((o0 ^ o1) & 0x80000000u) ? 1.0f : -1.0f;
    vp[c] = (bf16)u;
    xl[j] = t; vl[j] = u;
    s1 += t; s2 += t * t; sv += u; sxv += t * u;
  }
  #pragma unroll
  for (int off = 1; off < 64; off <<= 1) {
    s1 += __shfl_xor(s1, off); s2 += __shfl_xor(s2, off);
    sv += __shfl_xor(sv, off); sxv += __shfl_xor(sxv, off);
  }
  const float mu = s1 * (1.f / 768.f);
  const float var = s2 * (1.f / 768.f) - mu * mu;
  const float rstd = rsqrtf(var + 1e-5f);
  const float mv = sv * (1.f / 768.f);
  const float mhv = rstd * (sxv * (1.f / 768.f) - mu * mv);
  const float* gp = g + l * 768;
  const float* bp = beta + l * 768;
  bf16* ap = a_buf + (size_t)l * LAY_A + (size_t)(2 * row) * 768;
  bf16* dp = ap + 768;
  #pragma unroll
  for (int j = 0; j < 12; ++j) {
    const int c = lane + 64 * j;
    const float xh = (xl[j] - mu) * rstd;
    ap[c] = (bf16)(xh * gp[c] + bp[c]);
    dp[c] = (bf16)(rstd * ((vl[j] - mv) - xh * mhv) * gp[c]);
  }
}

// --------------------------- scan + state update ---------------------------
__global__ __launch_bounds__(256) void scan_kernel(
    const float* __restrict__ resA, float* __restrict__ states)
{
  const size_t i = (size_t)blockIdx.x * 256 + threadIdx.x;
  float run = resA[i];
  states[LAY_S + i] += run;
  #pragma unroll
  for (int l = 1; l < 12; ++l) {
    const float b  = resA[(size_t)l * LAY_A + i];
    const float Aa = resA[(size_t)l * LAY_A + LAY_S + i];
    run = b + Aa * run;
    states[(size_t)(l + 1) * LAY_S + i] += run;
  }
}

// ------------------------------- launcher ----------------------------------
extern "C" void kernel_launch(void* const* d_in, const int* in_sizes, int n_in,
                              void* d_out, int out_size, void* d_ws, size_t ws_size,
                              hipStream_t stream)
{
  const float* x0   = (const float*)d_in[0];
  const float* w1   = (const float*)d_in[1];
  const float* b1   = (const float*)d_in[2];
  const float* w2   = (const float*)d_in[3];
  const float* b2   = (const float*)d_in[4];
  const float* g    = (const float*)d_in[5];
  const float* beta = (const float*)d_in[6];

  char* ws = (char*)d_ws;
  size_t off = 0;
  auto alloc = [&](size_t bytes) -> void* {
    void* p = ws + off;
    off += (bytes + 255) & ~(size_t)255;
    return p;
  };
  bf16*  w1t    = (bf16*)alloc(2ULL * 12 * LAY_W);
  bf16*  w2t    = (bf16*)alloc(2ULL * 12 * LAY_W);
  float* states = (float*)alloc(4ULL * 13 * LAY_S);
  bf16*  a_buf  = (bf16*)alloc(2ULL * 12 * LAY_A);
  bf16*  zh     = (bf16*)alloc(2ULL * 12 * LAY_Z);
  float* resA   = (float*)alloc(4ULL * 12 * LAY_A);
  bf16*  vbuf   = (bf16*)alloc(2ULL * 12 * LAY_S);

  transpose_kernel<<<dim3(96, 24, 12), 256, 0, stream>>>(w1, w1t, 768, 3072);
  transpose_kernel<<<dim3(24, 96, 12), 256, 0, stream>>>(w2, w2t, 3072, 768);
  hipMemcpyAsync(states, x0, 4ULL * LAY_S, hipMemcpyDeviceToDevice, stream);

  // warm start: states[l+1] = block_l(x0)
  ln_warm_kernel<<<256, 256, 0, stream>>>(x0, g, beta, a_buf);
  gemm_dbuf<0><<<576, 512, 0, stream>>>(a_buf, w1t, zh, states, resA, vbuf,
                                        b1, b2, x0, 4);
  gemm_dbuf<2><<<144, 512, 0, stream>>>(zh, w2t, nullptr, states, resA, vbuf,
                                        b1, b2, x0, 4);

  for (int it = 0; it < 2; ++it) {
    uint32_t k1, k2;
    threefry2x32(0u, 42u, 0u, (uint32_t)it, k1, k2);
    ln_iter_kernel<<<3072, 256, 0, stream>>>(states, vbuf, g, beta, a_buf,
                                             k1, k2);
    gemm_dbuf<1><<<1152, 512, 0, stream>>>(a_buf, w1t, zh, states, resA, vbuf,
                                           b1, b2, x0, 8);
    gemm_dbuf<3><<<576, 512, 0, stream>>>(zh, w2t, nullptr, states, resA, vbuf,
                                          b1, b2, x0, 8);
    scan_kernel<<<3072, 256, 0, stream>>>(resA, states);
  }

  hipMemcpyAsync(d_out, states + 12ULL * LAY_S, 4ULL * LAY_S,
                 hipMemcpyDeviceToDevice, stream);
}

// Round 5
// 1130.251 us; speedup vs baseline: 1.4592x; 1.0229x over previous
//
#include <hip/hip_runtime.h>
#include <hip/hip_bf16.h>
#include <stdint.h>

// ---------------------------------------------------------------------------
// DEER forward, MI355X. L=12, B=2, T=512, C=768, F=3072, M=B*T=1024.
// bf16 MFMA GEMMs (fp32 accum), analytic JVP, threefry2x32 Rademacher v.
// R5: R4 (passing, absmax 0.1875) with ONE change: the GEMM K-loop now uses
//     a counted-vmcnt pipeline (T3/T4) instead of __syncthreads drains.
//     Per K-tile: barrier -> STAGE(t+1) -> s_waitcnt vmcnt(NCH) [tile t
//     landed, t+1 stays in flight under MFMA] -> barrier -> COMPUTE(t).
//     All barriers sandwiched in compiler memory fences (no ds_read hoist).
// ---------------------------------------------------------------------------

typedef __bf16 bf16;
typedef __bf16 bf16x8 __attribute__((ext_vector_type(8)));
typedef float f32x4 __attribute__((ext_vector_type(4)));

#define LAY_A   1572864   // 2048*768
#define LAY_W   2359296   // 3072*768
#define LAY_Z   6291456   // 2048*3072
#define LAY_S   786432    // 1024*768

#define GLDS16(gp, lp) __builtin_amdgcn_global_load_lds(                      \
    (const __attribute__((address_space(1))) void*)(gp),                      \
    (__attribute__((address_space(3))) void*)(lp), 16, 0, 0)

#define WAITVM(N) asm volatile("s_waitcnt vmcnt(%0)" :: "n"(N) : "memory")
#define CFENCE()  asm volatile("" ::: "memory")

// ------------------------- threefry2x32 (host+device) ----------------------
#define TF_ROT(x0, x1, n) { x0 += x1; x1 = (x1 << n) | (x1 >> (32 - n)); x1 ^= x0; }
__host__ __device__ __forceinline__ void threefry2x32(
    uint32_t k1, uint32_t k2, uint32_t c0, uint32_t c1, uint32_t& o0, uint32_t& o1)
{
  const uint32_t ks2 = k1 ^ k2 ^ 0x1BD11BDAu;
  uint32_t x0 = c0 + k1, x1 = c1 + k2;
  TF_ROT(x0,x1,13) TF_ROT(x0,x1,15) TF_ROT(x0,x1,26) TF_ROT(x0,x1,6)
  x0 += k2;  x1 += ks2 + 1u;
  TF_ROT(x0,x1,17) TF_ROT(x0,x1,29) TF_ROT(x0,x1,16) TF_ROT(x0,x1,24)
  x0 += ks2; x1 += k1 + 2u;
  TF_ROT(x0,x1,13) TF_ROT(x0,x1,15) TF_ROT(x0,x1,26) TF_ROT(x0,x1,6)
  x0 += k1;  x1 += k2 + 3u;
  TF_ROT(x0,x1,17) TF_ROT(x0,x1,29) TF_ROT(x0,x1,16) TF_ROT(x0,x1,24)
  x0 += k2;  x1 += ks2 + 4u;
  TF_ROT(x0,x1,13) TF_ROT(x0,x1,15) TF_ROT(x0,x1,26) TF_ROT(x0,x1,6)
  x0 += ks2; x1 += k1 + 5u;
  o0 = x0; o1 = x1;
}

// --------------------- weight transpose fp32 -> bf16^T ---------------------
__global__ __launch_bounds__(256) void transpose_kernel(
    const float* __restrict__ w, bf16* __restrict__ wt, int R, int Cc)
{
  __shared__ float tile[32][33];
  const int l = blockIdx.z;
  const float* wp = w + (size_t)l * R * Cc;
  bf16* wtp = wt + (size_t)l * R * Cc;
  const int c0 = blockIdx.x * 32;
  const int r0 = blockIdx.y * 32;
  const int tx = threadIdx.x & 31, ty = threadIdx.x >> 5;
  #pragma unroll
  for (int q = 0; q < 4; ++q)
    tile[ty + q * 8][tx] = wp[(size_t)(r0 + ty + q * 8) * Cc + c0 + tx];
  __syncthreads();
  #pragma unroll
  for (int q = 0; q < 4; ++q)
    wtp[(size_t)(c0 + ty + q * 8) * R + r0 + tx] = (bf16)tile[tx][ty + q * 8];
}

// ------------------------------ gelu helper --------------------------------
__device__ __forceinline__ void gelu2(float z, float& h, float& dg)
{
  const float z2 = z * z;
  const float u = 0.7978845608028654f * (z + 0.044715f * z2 * z);
  const float t = tanhf(u);
  h = 0.5f * z * (1.f + t);
  dg = 0.5f * (1.f + t) +
       0.5f * z * (1.f - t * t) * 0.7978845608028654f * (1.f + 0.134145f * z2);
}

// ------------------------------ GEMM core ----------------------------------
// 256xTN tile, BK=64, 512 threads = 8 waves (2M x 4N). Counted-vmcnt
// pipeline; STAGE/COMPUTE and epilogues identical to R4 (verified).
// MODE 0: gemm1 warm  (M=1024): zh = gelu(acc + b1), all rows.
// MODE 1: gemm1 iter  (M=2048 interleaved): even h=gelu(z), odd dh=dg*dz.
// MODE 2: gemm2 warm : states[l+1] = acc + b2 + x0.
// MODE 3: gemm2 iter  (TN=128, interleaved): even res, odd A = 1 + acc*v.
template <int MODE>
__global__ __launch_bounds__(512, 2) void gemm_dbuf(
    const bf16* __restrict__ Abase, const bf16* __restrict__ Bbase,
    bf16* __restrict__ zh_out, float* __restrict__ states,
    float* __restrict__ resA, const bf16* __restrict__ vbuf,
    const float* __restrict__ bias1, const float* __restrict__ b2,
    const float* __restrict__ x0, int Mt)
{
  constexpr int LDAB  = (MODE <= 1) ? 768 : 3072;
  constexpr int NKT   = (MODE <= 1) ? 12 : 48;      // K/64
  constexpr int NTN   = (MODE <= 1) ? 12 : ((MODE == 2) ? 3 : 6);
  constexpr int TN    = (MODE == 3) ? 128 : 256;
  constexpr int NFRAG = TN / 64;
  constexpr int ACH   = 32;                 // A chunks (256 rows / 8)
  constexpr int BCH   = TN / 8;             // B chunks
  constexpr int NCH   = (ACH + BCH) / 8;    // loads per thread per tile
  constexpr int ABYTES = 32768;
  constexpr int TILE  = ABYTES + BCH * 1024;
  constexpr size_t LSA = (MODE <= 1) ? LAY_A : LAY_Z;

  __shared__ __align__(16) char lds[2][TILE];

  const int tid  = threadIdx.x;
  const int lane = tid & 63;
  const int wid  = tid >> 6;           // 0..7
  const int wr   = wid >> 2;           // 0..1  (M half)
  const int wc   = wid & 3;            // 0..3  (N quarter)
  const int r16  = lane & 15;
  const int hi   = lane >> 4;          // 0..3

  // T1: XCD-aware bijective swizzle (grids are multiples of 8)
  const int nwg = gridDim.x;
  const int bid = blockIdx.x;
  const int swz = (bid & 7) * (nwg >> 3) + (bid >> 3);
  const int per_l = Mt * NTN;
  const int l   = swz / per_l;
  const int rr_ = swz - l * per_l;
  const int mt  = rr_ / NTN;
  const int nt  = rr_ - mt * NTN;
  const int m0  = mt * 256, n0 = nt * TN;

  const bf16* A = Abase + (size_t)l * LSA   + (size_t)m0 * LDAB;
  const bf16* B = Bbase + (size_t)l * LAY_W + (size_t)n0 * LDAB;

  const int rsub = lane >> 3;               // 0..7 row within chunk
  const int c8   = (lane & 7) ^ rsub;       // swizzled 16B slot (involution)
  auto STAGE = [&](char* dst, int kt) {
    #pragma unroll
    for (int j = 0; j < NCH; ++j) {
      const int chunk = j * 8 + wid;
      if (chunk < ACH) {
        const int row = chunk * 8 + rsub;
        GLDS16(A + (size_t)row * LDAB + kt + c8 * 8, dst + chunk * 1024);
      } else {
        const int row = (chunk - ACH) * 8 + rsub;
        GLDS16(B + (size_t)row * LDAB + kt + c8 * 8,
               dst + ABYTES + (chunk - ACH) * 1024);
      }
    }
  };

  f32x4 acc[8][NFRAG] = {};

  auto COMPUTE = [&](const char* buf) {
    const char* As = buf;
    const char* Bs = buf + ABYTES;
    const int xw = (r16 & 7) << 4;        // read-side XOR (matches staging)
    #pragma unroll
    for (int kk = 0; kk < 2; ++kk) {
      const int cb = kk * 64;
      bf16x8 bfrag[NFRAG];
      #pragma unroll
      for (int ni = 0; ni < NFRAG; ++ni) {
        const int rn = wc * (TN / 4) + ni * 16 + r16;
        bfrag[ni] = *(const bf16x8*)(Bs + rn * 128 + ((cb + hi * 16) ^ xw));
      }
      #pragma unroll
      for (int mh = 0; mh < 2; ++mh) {
        bf16x8 afrag[4];
        #pragma unroll
        for (int q = 0; q < 4; ++q) {
          const int rm = wr * 128 + (mh * 4 + q) * 16 + r16;
          afrag[q] = *(const bf16x8*)(As + rm * 128 + ((cb + hi * 16) ^ xw));
        }
        #pragma unroll
        for (int q = 0; q < 4; ++q)
          #pragma unroll
          for (int ni = 0; ni < NFRAG; ++ni)
            acc[mh * 4 + q][ni] = __builtin_amdgcn_mfma_f32_16x16x32_bf16(
                afrag[q], bfrag[ni], acc[mh * 4 + q][ni], 0, 0, 0);
      }
    }
  };

  // ---- counted-vmcnt pipeline (R5) ----
  // invariant entering COMPUTE(t): tile t landed in buf[t&1] on ALL waves;
  // tile t+1's NCH loads (per thread) in flight into buf[(t+1)&1].
  STAGE(lds[0], 0);
  STAGE(lds[1], 64);
  WAITVM(NCH);                         // tile 0 landed; tile 1 in flight
  __builtin_amdgcn_s_barrier();
  CFENCE();
  COMPUTE(lds[0]);
  #pragma unroll 1
  for (int t = 1; t < NKT; ++t) {
    CFENCE();
    __builtin_amdgcn_s_barrier();      // all waves done reading buf[(t+1)&1]
    CFENCE();
    if (t + 1 < NKT) {
      STAGE(lds[(t + 1) & 1], (t + 1) * 64);
      WAITVM(NCH);                     // tile t landed; t+1 stays in flight
    } else {
      WAITVM(0);                       // last tile: drain
    }
    __builtin_amdgcn_s_barrier();      // cross-wave: tile t visible to all
    CFENCE();
    COMPUTE(lds[t & 1]);
  }

  // ------------------------------ epilogue ---------------------------------
  #pragma unroll
  for (int mi = 0; mi < 8; ++mi) {
    const int row0 = m0 + wr * 128 + mi * 16 + hi * 4;
    #pragma unroll
    for (int ni = 0; ni < NFRAG; ++ni) {
      const int col = n0 + wc * (TN / 4) + ni * 16 + r16;
      if (MODE == 0) {                  // warm gemm1: h = gelu(z), all rows
        bf16* Cp = zh_out + (size_t)l * LAY_Z;
        const float bias = bias1[l * 3072 + col];
        #pragma unroll
        for (int r = 0; r < 4; ++r) {
          float h, dg;
          gelu2(acc[mi][ni][r] + bias, h, dg);
          Cp[(size_t)(row0 + r) * 3072 + col] = (bf16)h;
        }
      } else if (MODE == 1) {           // iter gemm1: row pairs (z, dz)
        bf16* Cp = zh_out + (size_t)l * LAY_Z;
        const float bias = bias1[l * 3072 + col];
        #pragma unroll
        for (int p = 0; p < 2; ++p) {
          float h, dg;
          gelu2(acc[mi][ni][2 * p] + bias, h, dg);
          Cp[(size_t)(row0 + 2 * p) * 3072 + col] = (bf16)h;
          Cp[(size_t)(row0 + 2 * p + 1) * 3072 + col] =
              (bf16)(dg * acc[mi][ni][2 * p + 1]);
        }
      } else if (MODE == 2) {           // warm gemm2
        float* Sp = states + (size_t)(l + 1) * LAY_S;
        const float bb = b2[l * 768 + col];
        #pragma unroll
        for (int r = 0; r < 4; ++r)
          Sp[(size_t)(row0 + r) * 768 + col] =
              acc[mi][ni][r] + bb + x0[(size_t)(row0 + r) * 768 + col];
      } else {                          // iter gemm2: row pairs (res, Adiag)
        float* Rp = resA + (size_t)l * LAY_A;
        const float bb = b2[l * 768 + col];
        #pragma unroll
        for (int p = 0; p < 2; ++p) {
          const int tok = (row0 >> 1) + p;          // rows row0+2p, +2p+1
          Rp[(size_t)tok * 768 + col] = acc[mi][ni][2 * p] + bb
              + states[(size_t)l * LAY_S + (size_t)tok * 768 + col]
              - states[(size_t)(l + 1) * LAY_S + (size_t)tok * 768 + col];
          const float vv = (float)vbuf[(size_t)l * LAY_S +
                                       (size_t)tok * 768 + col];
          Rp[LAY_S + (size_t)tok * 768 + col] =
              1.0f + acc[mi][ni][2 * p + 1] * vv;
        }
      }
    }
  }
}

// ------------------------------- LayerNorm ---------------------------------
__global__ __launch_bounds__(256) void ln_warm_kernel(
    const float* __restrict__ x0, const float* __restrict__ g,
    const float* __restrict__ beta, bf16* __restrict__ a_buf)
{
  const int row = blockIdx.x * 4 + (threadIdx.x >> 6);
  const int lane = threadIdx.x & 63;
  const float* x = x0 + (size_t)row * 768;
  float xl[12];
  float s1 = 0.f, s2 = 0.f;
  #pragma unroll
  for (int j = 0; j < 12; ++j) {
    float t = x[lane + 64 * j];
    xl[j] = t; s1 += t; s2 += t * t;
  }
  #pragma unroll
  for (int off = 1; off < 64; off <<= 1) {
    s1 += __shfl_xor(s1, off);
    s2 += __shfl_xor(s2, off);
  }
  const float mu = s1 * (1.f / 768.f);
  const float var = s2 * (1.f / 768.f) - mu * mu;
  const float rstd = rsqrtf(var + 1e-5f);
  float xh[12];
  #pragma unroll
  for (int j = 0; j < 12; ++j) xh[j] = (xl[j] - mu) * rstd;
  for (int l = 0; l < 12; ++l) {
    const float* gp = g + l * 768;
    const float* bp = beta + l * 768;
    bf16* ap = a_buf + (size_t)l * LAY_A + (size_t)row * 768;
    #pragma unroll
    for (int j = 0; j < 12; ++j) {
      const int c = lane + 64 * j;
      ap[c] = (bf16)(xh[j] * gp[c] + bp[c]);
    }
  }
}

// iter: LN + LN-JVP with tangent v (v generated inline via threefry).
// Writes interleaved rows: token row -> a at 2*row, du at 2*row+1.
__global__ __launch_bounds__(256) void ln_iter_kernel(
    const float* __restrict__ states, bf16* __restrict__ vbuf,
    const float* __restrict__ g, const float* __restrict__ beta,
    bf16* __restrict__ a_buf, uint32_t k1, uint32_t k2)
{
  const int gr = blockIdx.x * 4 + (threadIdx.x >> 6);
  const int l = gr >> 10;
  const int row = gr & 1023;
  const int lane = threadIdx.x & 63;
  const float* x = states + (size_t)l * LAY_S + (size_t)row * 768;
  bf16* vp = vbuf + (size_t)gr * 768;
  float xl[12], vl[12];
  float s1 = 0.f, s2 = 0.f, sv = 0.f, sxv = 0.f;
  #pragma unroll
  for (int j = 0; j < 12; ++j) {
    const int c = lane + 64 * j;
    const float t = x[c];
    uint32_t o0, o1;
    threefry2x32(k1, k2, 0u, (uint32_t)gr * 768u + (uint32_t)c, o0, o1);
    const float u = ((o0 ^ o1) & 0x80000000u) ? 1.0f : -1.0f;
    vp[c] = (bf16)u;
    xl[j] = t; vl[j] = u;
    s1 += t; s2 += t * t; sv += u; sxv += t * u;
  }
  #pragma unroll
  for (int off = 1; off < 64; off <<= 1) {
    s1 += __shfl_xor(s1, off); s2 += __shfl_xor(s2, off);
    sv += __shfl_xor(sv, off); sxv += __shfl_xor(sxv, off);
  }
  const float mu = s1 * (1.f / 768.f);
  const float var = s2 * (1.f / 768.f) - mu * mu;
  const float rstd = rsqrtf(var + 1e-5f);
  const float mv = sv * (1.f / 768.f);
  const float mhv = rstd * (sxv * (1.f / 768.f) - mu * mv);
  const float* gp = g + l * 768;
  const float* bp = beta + l * 768;
  bf16* ap = a_buf + (size_t)l * LAY_A + (size_t)(2 * row) * 768;
  bf16* dp = ap + 768;
  #pragma unroll
  for (int j = 0; j < 12; ++j) {
    const int c = lane + 64 * j;
    const float xh = (xl[j] - mu) * rstd;
    ap[c] = (bf16)(xh * gp[c] + bp[c]);
    dp[c] = (bf16)(rstd * ((vl[j] - mv) - xh * mhv) * gp[c]);
  }
}

// --------------------------- scan + state update ---------------------------
__global__ __launch_bounds__(256) void scan_kernel(
    const float* __restrict__ resA, float* __restrict__ states)
{
  const size_t i = (size_t)blockIdx.x * 256 + threadIdx.x;
  float run = resA[i];
  states[LAY_S + i] += run;
  #pragma unroll
  for (int l = 1; l < 12; ++l) {
    const float b  = resA[(size_t)l * LAY_A + i];
    const float Aa = resA[(size_t)l * LAY_A + LAY_S + i];
    run = b + Aa * run;
    states[(size_t)(l + 1) * LAY_S + i] += run;
  }
}

// ------------------------------- launcher ----------------------------------
extern "C" void kernel_launch(void* const* d_in, const int* in_sizes, int n_in,
                              void* d_out, int out_size, void* d_ws, size_t ws_size,
                              hipStream_t stream)
{
  const float* x0   = (const float*)d_in[0];
  const float* w1   = (const float*)d_in[1];
  const float* b1   = (const float*)d_in[2];
  const float* w2   = (const float*)d_in[3];
  const float* b2   = (const float*)d_in[4];
  const float* g    = (const float*)d_in[5];
  const float* beta = (const float*)d_in[6];

  char* ws = (char*)d_ws;
  size_t off = 0;
  auto alloc = [&](size_t bytes) -> void* {
    void* p = ws + off;
    off += (bytes + 255) & ~(size_t)255;
    return p;
  };
  bf16*  w1t    = (bf16*)alloc(2ULL * 12 * LAY_W);
  bf16*  w2t    = (bf16*)alloc(2ULL * 12 * LAY_W);
  float* states = (float*)alloc(4ULL * 13 * LAY_S);
  bf16*  a_buf  = (bf16*)alloc(2ULL * 12 * LAY_A);
  bf16*  zh     = (bf16*)alloc(2ULL * 12 * LAY_Z);
  float* resA   = (float*)alloc(4ULL * 12 * LAY_A);
  bf16*  vbuf   = (bf16*)alloc(2ULL * 12 * LAY_S);

  transpose_kernel<<<dim3(96, 24, 12), 256, 0, stream>>>(w1, w1t, 768, 3072);
  transpose_kernel<<<dim3(24, 96, 12), 256, 0, stream>>>(w2, w2t, 3072, 768);
  hipMemcpyAsync(states, x0, 4ULL * LAY_S, hipMemcpyDeviceToDevice, stream);

  // warm start: states[l+1] = block_l(x0)
  ln_warm_kernel<<<256, 256, 0, stream>>>(x0, g, beta, a_buf);
  gemm_dbuf<0><<<576, 512, 0, stream>>>(a_buf, w1t, zh, states, resA, vbuf,
                                        b1, b2, x0, 4);
  gemm_dbuf<2><<<144, 512, 0, stream>>>(zh, w2t, nullptr, states, resA, vbuf,
                                        b1, b2, x0, 4);

  for (int it = 0; it < 2; ++it) {
    uint32_t k1, k2;
    threefry2x32(0u, 42u, 0u, (uint32_t)it, k1, k2);
    ln_iter_kernel<<<3072, 256, 0, stream>>>(states, vbuf, g, beta, a_buf,
                                             k1, k2);
    gemm_dbuf<1><<<1152, 512, 0, stream>>>(a_buf, w1t, zh, states, resA, vbuf,
                                           b1, b2, x0, 8);
    gemm_dbuf<3><<<576, 512, 0, stream>>>(zh, w2t, nullptr, states, resA, vbuf,
                                          b1, b2, x0, 8);
    scan_kernel<<<3072, 256, 0, stream>>>(resA, states);
  }

  hipMemcpyAsync(d_out, states + 12ULL * LAY_S, 4ULL * LAY_S,
                 hipMemcpyDeviceToDevice, stream);
}